// Round 2
// baseline (2214.853 us; speedup 1.0000x reference)
//
#include <hip/hip_runtime.h>

typedef __attribute__((ext_vector_type(8))) short short8;
typedef __attribute__((ext_vector_type(4))) float f32x4;

#define GLBP(p) ((const __attribute__((address_space(1))) void*)(p))
#define LDSP(p) ((__attribute__((address_space(3))) void*)(p))

__device__ __forceinline__ float bf2f(unsigned short u) {
  return __uint_as_float(((unsigned int)u) << 16);
}
__device__ __forceinline__ unsigned short f2bf(float f) {
  unsigned int u = __float_as_uint(f);
  u += 0x7fff + ((u >> 16) & 1);
  return (unsigned short)(u >> 16);
}

// global token -> (batch, pixel-y, pixel-x); windows are 14x14, 5x5 grid/batch
__device__ __forceinline__ void tok2pix(int gt, int& b, int& py, int& px) {
  int w = gt / 196, t = gt - w * 196;
  b = w / 25;
  int wr = w - b * 25;
  int wy = wr / 5, wx = wr - wy * 5;
  int ty = t / 14;
  py = wy * 14 + ty;
  px = wx * 14 + (t - ty * 14);
}

// ---------------- weight transpose fp32(K,N) -> bf16(N,K) ----------------
__global__ void k_transpose(const float* __restrict__ W, unsigned short* __restrict__ Wt,
                            int K, int N) {
  __shared__ float tile[32][33];
  int tx = threadIdx.x, ty = threadIdx.y;
  int n0 = blockIdx.x * 32, k0 = blockIdx.y * 32;
#pragma unroll
  for (int i = 0; i < 4; ++i)
    tile[ty + 8 * i][tx] = W[(size_t)(k0 + ty + 8 * i) * N + n0 + tx];
  __syncthreads();
#pragma unroll
  for (int i = 0; i < 4; ++i)
    Wt[(size_t)(n0 + ty + 8 * i) * K + k0 + tx] = f2bf(tile[tx][ty + 8 * i]);
}

// ---------------- LN1 (windowed gather from image) -> bf16 token rows ----------------
__global__ __launch_bounds__(256) void k_ln1(const float* __restrict__ x,
                                             const float* __restrict__ g,
                                             const float* __restrict__ be,
                                             unsigned short* __restrict__ A1,
                                             int w0, int ctok) {
  int m = blockIdx.x, tid = threadIdx.x;
  int b, py, px;
  tok2pix(w0 * 196 + m, b, py, px);
  bool valid = (m < ctok) && (py < 64) && (px < 64);
  const float* row = x + ((size_t)((b * 64 + py) * 64 + px)) * 1280;
  float v[5];
#pragma unroll
  for (int i = 0; i < 5; ++i) v[i] = valid ? row[tid + 256 * i] : 0.f;
  float s = 0.f, ss = 0.f;
#pragma unroll
  for (int i = 0; i < 5; ++i) { s += v[i]; ss += v[i] * v[i]; }
#pragma unroll
  for (int o = 32; o > 0; o >>= 1) { s += __shfl_down(s, o); ss += __shfl_down(ss, o); }
  __shared__ float rs[8];
  int wid = tid >> 6, lane = tid & 63;
  if (lane == 0) { rs[wid] = s; rs[wid + 4] = ss; }
  __syncthreads();
  s = rs[0] + rs[1] + rs[2] + rs[3];
  ss = rs[4] + rs[5] + rs[6] + rs[7];
  float mu = s * (1.f / 1280.f);
  float var = ss * (1.f / 1280.f) - mu * mu;
  float rinv = rsqrtf(var + 1e-6f);
  unsigned short* o1 = A1 + (size_t)m * 1280;
#pragma unroll
  for (int i = 0; i < 5; ++i) {
    int c = tid + 256 * i;
    o1[c] = f2bf((v[i] - mu) * rinv * g[c] + be[c]);
  }
}

// ---------------- LN2 over bf16 attn_out rows -> bf16 ----------------
__global__ __launch_bounds__(256) void k_ln2(const unsigned short* __restrict__ AT,
                                             const float* __restrict__ g,
                                             const float* __restrict__ be,
                                             unsigned short* __restrict__ A2) {
  int m = blockIdx.x, tid = threadIdx.x;
  const unsigned short* row = AT + (size_t)m * 1280;
  float v[5];
#pragma unroll
  for (int i = 0; i < 5; ++i) v[i] = bf2f(row[tid + 256 * i]);
  float s = 0.f, ss = 0.f;
#pragma unroll
  for (int i = 0; i < 5; ++i) { s += v[i]; ss += v[i] * v[i]; }
#pragma unroll
  for (int o = 32; o > 0; o >>= 1) { s += __shfl_down(s, o); ss += __shfl_down(ss, o); }
  __shared__ float rs[8];
  int wid = tid >> 6, lane = tid & 63;
  if (lane == 0) { rs[wid] = s; rs[wid + 4] = ss; }
  __syncthreads();
  s = rs[0] + rs[1] + rs[2] + rs[3];
  ss = rs[4] + rs[5] + rs[6] + rs[7];
  float mu = s * (1.f / 1280.f);
  float var = ss * (1.f / 1280.f) - mu * mu;
  float rinv = rsqrtf(var + 1e-6f);
  unsigned short* o1 = A2 + (size_t)m * 1280;
#pragma unroll
  for (int i = 0; i < 5; ++i) {
    int c = tid + 256 * i;
    o1[c] = f2bf((v[i] - mu) * rinv * g[c] + be[c]);
  }
}

// ---------------- 128x128 bf16 GEMM (m97 structure), fused epilogues ----------------
// C[M,N] = A[M,K] * Bt[N,K]^T
// EPI 0: +bias -> bf16 (QKV)         EPI 2: +bias + exact gelu -> bf16 (MLP1)
// EPI 1: +bias + window-residual(x) -> bf16 ATTN (proj)
// EPI 3: +bias + attn-residual -> f32 d_out, window->image crop (MLP2)
template <int EPI>
__global__ __launch_bounds__(256) void k_gemm(const unsigned short* __restrict__ A,
                                              const unsigned short* __restrict__ Bt,
                                              int K, int N,
                                              const float* __restrict__ bias,
                                              void* __restrict__ outp,
                                              const float* __restrict__ xres,
                                              const unsigned short* __restrict__ attnres,
                                              int w0, int ctok) {
  __shared__ unsigned short As[128 * 32];
  __shared__ unsigned short Bs[128 * 32];
  int tid = threadIdx.x, wid = tid >> 6, lane = tid & 63;
  int mBase = blockIdx.y * 128, nBase = blockIdx.x * 128;
  int wr = wid >> 1, wc = wid & 1;
  int la = lane & 15, lg = lane >> 4;
  const unsigned short* Ab = A + (size_t)mBase * K;
  const unsigned short* Bb = Bt + (size_t)nBase * K;
  const f32x4 z4 = {0.f, 0.f, 0.f, 0.f};
  f32x4 acc[4][4];
#pragma unroll
  for (int i = 0; i < 4; ++i)
#pragma unroll
    for (int j = 0; j < 4; ++j) acc[i][j] = z4;

  int c0 = wid * 64 + lane;
  int r0 = c0 >> 2, o0 = (c0 & 3) * 8;
  int c1 = 256 + c0;
  int r1 = c1 >> 2, o1 = (c1 & 3) * 8;

  for (int k0 = 0; k0 < K; k0 += 32) {
    __builtin_amdgcn_global_load_lds(GLBP(Ab + (size_t)r0 * K + k0 + o0),
                                     LDSP(As + (wid * 64) * 8), 16, 0, 0);
    __builtin_amdgcn_global_load_lds(GLBP(Bb + (size_t)r0 * K + k0 + o0),
                                     LDSP(Bs + (wid * 64) * 8), 16, 0, 0);
    __builtin_amdgcn_global_load_lds(GLBP(Ab + (size_t)r1 * K + k0 + o1),
                                     LDSP(As + (256 + wid * 64) * 8), 16, 0, 0);
    __builtin_amdgcn_global_load_lds(GLBP(Bb + (size_t)r1 * K + k0 + o1),
                                     LDSP(Bs + (256 + wid * 64) * 8), 16, 0, 0);
    __syncthreads();
    short8 af[4], bfr[4];
#pragma unroll
    for (int i = 0; i < 4; ++i)
      af[i] = *(const short8*)(As + (wr * 64 + i * 16 + la) * 32 + lg * 8);
#pragma unroll
    for (int i = 0; i < 4; ++i)
      bfr[i] = *(const short8*)(Bs + (wc * 64 + i * 16 + la) * 32 + lg * 8);
#pragma unroll
    for (int mi = 0; mi < 4; ++mi)
#pragma unroll
      for (int ni = 0; ni < 4; ++ni)
        acc[mi][ni] = __builtin_amdgcn_mfma_f32_16x16x32_bf16(af[mi], bfr[ni], acc[mi][ni], 0, 0, 0);
    __syncthreads();
  }

#pragma unroll
  for (int mi = 0; mi < 4; ++mi) {
#pragma unroll
    for (int ni = 0; ni < 4; ++ni) {
      int col = nBase + wc * 64 + ni * 16 + la;
      float bcol = bias[col];
#pragma unroll
      for (int j = 0; j < 4; ++j) {
        int row = mBase + wr * 64 + mi * 16 + lg * 4 + j;
        float v = acc[mi][ni][j] + bcol;
        if (EPI == 0) {
          ((unsigned short*)outp)[(size_t)row * N + col] = f2bf(v);
        } else if (EPI == 2) {
          float gg = 0.5f * v * (1.f + erff(v * 0.70710678118654752f));
          ((unsigned short*)outp)[(size_t)row * N + col] = f2bf(gg);
        } else if (EPI == 1) {
          if (row < ctok) {
            int b, py, px;
            tok2pix(w0 * 196 + row, b, py, px);
            float wv = (py < 64 && px < 64)
                           ? xres[((size_t)((b * 64 + py) * 64 + px)) * 1280 + col]
                           : 0.f;
            ((unsigned short*)outp)[(size_t)row * 1280 + col] = f2bf(v + wv);
          }
        } else {
          if (row < ctok) {
            int b, py, px;
            tok2pix(w0 * 196 + row, b, py, px);
            if (py < 64 && px < 64)
              ((float*)outp)[((size_t)((b * 64 + py) * 64 + px)) * 1280 + col] =
                  v + bf2f(attnres[(size_t)row * 1280 + col]);
          }
        }
      }
    }
  }
}

// ---------------- decomposed rel-pos bias: B[wh][t][0..13]=bias_h(ky), [14..27]=bias_w(kx) ----------------
__global__ __launch_bounds__(256) void k_relbias(const unsigned short* __restrict__ qkv,
                                                 const float* __restrict__ rph,
                                                 const float* __restrict__ rpw,
                                                 float* __restrict__ B) {
  int wh = blockIdx.x;
  int w = wh >> 4, nh = wh & 15;
  const unsigned short* qb = qkv + (size_t)w * 196 * 3840 + nh * 80;
  for (int id = threadIdx.x; id < 196 * 28; id += 256) {
    int t = id / 28, which = id - t * 28;
    int y = t / 14, xx = t - y * 14;
    const float* R = (which < 14) ? (rph + (size_t)(y - which + 13) * 80)
                                  : (rpw + (size_t)(xx - (which - 14) + 13) * 80);
    const unsigned short* q = qb + (size_t)t * 3840;
    float acc = 0.f;
#pragma unroll
    for (int d8 = 0; d8 < 10; ++d8) {
      short8 qv = *(const short8*)(q + d8 * 8);
      const float4* Rv = (const float4*)(R + d8 * 8);
      float4 ra = Rv[0], rb = Rv[1];
      acc += bf2f((unsigned short)qv[0]) * ra.x + bf2f((unsigned short)qv[1]) * ra.y +
             bf2f((unsigned short)qv[2]) * ra.z + bf2f((unsigned short)qv[3]) * ra.w +
             bf2f((unsigned short)qv[4]) * rb.x + bf2f((unsigned short)qv[5]) * rb.y +
             bf2f((unsigned short)qv[6]) * rb.z + bf2f((unsigned short)qv[7]) * rb.w;
    }
    B[(size_t)wh * (196 * 28) + id] = acc;
  }
}

// ---------------- attention: one block per (window, head) ----------------
__global__ __launch_bounds__(256) void k_attn(const unsigned short* __restrict__ qkv,
                                              const float* __restrict__ Bias,
                                              unsigned short* __restrict__ AO) {
  __shared__ unsigned short Qs[208 * 96];
  __shared__ unsigned short Ks[208 * 96];
  __shared__ unsigned short Vt[80 * 224];
  __shared__ unsigned short Ps[4][16 * 224];
  int wh = blockIdx.x;
  int w = wh >> 4, nh = wh & 15;
  int tid = threadIdx.x, wid = tid >> 6, lane = tid & 63;
  const unsigned short* base = qkv + (size_t)w * 196 * 3840 + nh * 80;
  short8 z8 = {0, 0, 0, 0, 0, 0, 0, 0};
  for (int c = tid; c < 208 * 12; c += 256) {
    int t = c / 12, d8 = (c - t * 12) * 8;
    short8 qv = z8, kv = z8;
    if (t < 196 && d8 < 80) {
      const unsigned short* p = base + (size_t)t * 3840 + d8;
      qv = *(const short8*)(p);
      kv = *(const short8*)(p + 1280);
    }
    *(short8*)(Qs + t * 96 + d8) = qv;
    *(short8*)(Ks + t * 96 + d8) = kv;
  }
  for (int c = tid; c < 208 * 10; c += 256) {
    int t = c / 10, d8 = (c - t * 10) * 8;
    short8 vv = z8;
    if (t < 196) vv = *(const short8*)(base + (size_t)t * 3840 + 2560 + d8);
#pragma unroll
    for (int e = 0; e < 8; ++e) Vt[(d8 + e) * 224 + t] = (unsigned short)vv[e];
  }
  for (int i = tid; i < 80 * 16; i += 256) Vt[(i >> 4) * 224 + 208 + (i & 15)] = 0;
  __syncthreads();

  int la = lane & 15, lg = lane >> 4;
  const float scale = 0.111803398874989485f;  // 80^-0.5
  const f32x4 z4 = {0.f, 0.f, 0.f, 0.f};
  unsigned short* P = Ps[wid];

  for (int rb = wid; rb < 13; rb += 4) {
    f32x4 s[13];
#pragma unroll
    for (int i = 0; i < 13; ++i) s[i] = z4;
#pragma unroll
    for (int kk = 0; kk < 3; ++kk) {
      short8 a = *(const short8*)(Qs + (rb * 16 + la) * 96 + kk * 32 + lg * 8);
#pragma unroll
      for (int ni = 0; ni < 13; ++ni) {
        short8 bb = *(const short8*)(Ks + (ni * 16 + la) * 96 + kk * 32 + lg * 8);
        s[ni] = __builtin_amdgcn_mfma_f32_16x16x32_bf16(a, bb, s[ni], 0, 0, 0);
      }
    }
#pragma unroll
    for (int j = 0; j < 4; ++j) {
      int rloc = lg * 4 + j;
      int t = rb * 16 + rloc;
      float v[13];
      float mx = -3e30f;
#pragma unroll
      for (int ci = 0; ci < 13; ++ci) {
        int key = ci * 16 + la;
        float val = s[ci][j] * scale;
        if (key < 196 && t < 196) {
          const float* Bp = Bias + ((size_t)wh * 196 + t) * 28;
          int ky = key / 14, kx = key - ky * 14;
          val += Bp[ky] + Bp[14 + kx];
        }
        if (key >= 196) val = -3e30f;
        v[ci] = val;
        mx = fmaxf(mx, val);
      }
#pragma unroll
      for (int o = 1; o < 16; o <<= 1) mx = fmaxf(mx, __shfl_xor(mx, o));
      float sum = 0.f;
#pragma unroll
      for (int ci = 0; ci < 13; ++ci) {
        float e = __expf(v[ci] - mx);
        v[ci] = e;
        sum += e;
      }
#pragma unroll
      for (int o = 1; o < 16; o <<= 1) sum += __shfl_xor(sum, o);
      float inv = 1.f / sum;
#pragma unroll
      for (int ci = 0; ci < 13; ++ci) P[rloc * 224 + ci * 16 + la] = f2bf(v[ci] * inv);
      P[rloc * 224 + 208 + la] = 0;
    }
    f32x4 o5[5];
#pragma unroll
    for (int i = 0; i < 5; ++i) o5[i] = z4;
#pragma unroll
    for (int kc = 0; kc < 7; ++kc) {
      short8 a = *(const short8*)(P + la * 224 + kc * 32 + lg * 8);
#pragma unroll
      for (int ni = 0; ni < 5; ++ni) {
        short8 bb = *(const short8*)(Vt + (ni * 16 + la) * 224 + kc * 32 + lg * 8);
        o5[ni] = __builtin_amdgcn_mfma_f32_16x16x32_bf16(a, bb, o5[ni], 0, 0, 0);
      }
    }
#pragma unroll
    for (int ni = 0; ni < 5; ++ni)
#pragma unroll
      for (int j = 0; j < 4; ++j) {
        int t = rb * 16 + lg * 4 + j;
        if (t < 196)
          AO[((size_t)w * 196 + t) * 1280 + nh * 80 + ni * 16 + la] = f2bf(o5[ni][j]);
      }
  }
}

extern "C" void kernel_launch(void* const* d_in, const int* in_sizes, int n_in,
                              void* d_out, int out_size, void* d_ws, size_t ws_size,
                              hipStream_t stream) {
  const float* x = (const float*)d_in[0];
  const float* ln1g = (const float*)d_in[1];
  const float* ln1b = (const float*)d_in[2];
  const float* qkvw = (const float*)d_in[3];
  const float* qkvb = (const float*)d_in[4];
  const float* projw = (const float*)d_in[5];
  const float* projb = (const float*)d_in[6];
  const float* rph = (const float*)d_in[7];
  const float* rpw = (const float*)d_in[8];
  const float* ln2g = (const float*)d_in[9];
  const float* ln2b = (const float*)d_in[10];
  const float* w1 = (const float*)d_in[11];
  const float* b1 = (const float*)d_in[12];
  const float* w2 = (const float*)d_in[13];
  const float* b2 = (const float*)d_in[14];
  float* out = (float*)d_out;

  // persistent: transposed bf16 weights at d_ws start
  const size_t woff = (3840ull * 1280 + 1280ull * 1280 + 5120ull * 1280 + 1280ull * 5120) * 2;
  // choose windows-per-chunk to fit ws_size (whole pipeline is window-chunkable)
  const int NWopts[8] = {50, 25, 20, 10, 5, 4, 2, 1};
  int NW = 0, Mb = 0;
  for (int i = 0; i < 8; ++i) {
    int nw = NWopts[i];
    int mb = ((nw * 196 + 127) / 128) * 128;
    size_t tot = woff + (size_t)mb * 2560 /*A1*/ + (size_t)mb * 7680 /*QKV*/ +
                 (size_t)mb * 2560 /*AO*/ + (size_t)nw * 16 * 196 * 28 * 4 /*BIAS*/ +
                 (size_t)mb * 2560 /*ATTN*/;
    if (tot <= ws_size) { NW = nw; Mb = mb; break; }
  }
  if (!NW) return;  // ws_size < ~44 MB: cannot run

  char* p = (char*)d_ws;
  unsigned short* qkvwT = (unsigned short*)p; p += 3840ull * 1280 * 2;
  unsigned short* projwT = (unsigned short*)p; p += 1280ull * 1280 * 2;
  unsigned short* w1T = (unsigned short*)p; p += 5120ull * 1280 * 2;
  unsigned short* w2T = (unsigned short*)p; p += 1280ull * 5120 * 2;
  unsigned short* A1 = (unsigned short*)p; p += (size_t)Mb * 2560;
  unsigned short* QKV = (unsigned short*)p; p += (size_t)Mb * 7680;
  unsigned short* AO = (unsigned short*)p; p += (size_t)Mb * 2560;
  float* BIAS = (float*)p; p += (size_t)NW * 16 * 196 * 28 * 4;
  unsigned short* ATTN = (unsigned short*)p;
  unsigned short* Hb = QKV;  // MLP hidden overlays QKV+AO (dead after attn/proj)
  unsigned short* A2 = A1;   // LN2 out overlays LN1 out (dead after QKV GEMM)

  k_transpose<<<dim3(120, 40), dim3(32, 8), 0, stream>>>(qkvw, qkvwT, 1280, 3840);
  k_transpose<<<dim3(40, 40), dim3(32, 8), 0, stream>>>(projw, projwT, 1280, 1280);
  k_transpose<<<dim3(160, 40), dim3(32, 8), 0, stream>>>(w1, w1T, 1280, 5120);
  k_transpose<<<dim3(40, 160), dim3(32, 8), 0, stream>>>(w2, w2T, 5120, 1280);

  int nchunks = (100 + NW - 1) / NW;
  for (int c = 0; c < nchunks; ++c) {
    int w0 = c * NW;
    int cw = (100 - w0 < NW) ? (100 - w0) : NW;
    int ctok = cw * 196;
    k_ln1<<<Mb, 256, 0, stream>>>(x, ln1g, ln1b, A1, w0, ctok);
    k_gemm<0><<<dim3(30, Mb / 128), 256, 0, stream>>>(A1, qkvwT, 1280, 3840, qkvb, (void*)QKV,
                                                      nullptr, nullptr, 0, 0);
    k_relbias<<<cw * 16, 256, 0, stream>>>(QKV, rph, rpw, BIAS);
    k_attn<<<cw * 16, 256, 0, stream>>>(QKV, BIAS, AO);
    k_gemm<1><<<dim3(10, Mb / 128), 256, 0, stream>>>(AO, projwT, 1280, 1280, projb, (void*)ATTN,
                                                      x, nullptr, w0, ctok);
    k_ln2<<<Mb, 256, 0, stream>>>(ATTN, ln2g, ln2b, A2);
    k_gemm<2><<<dim3(40, Mb / 128), 256, 0, stream>>>(A2, w1T, 1280, 5120, b1, (void*)Hb,
                                                      nullptr, nullptr, 0, 0);
    k_gemm<3><<<dim3(10, Mb / 128), 256, 0, stream>>>(Hb, w2T, 5120, 1280, b2, (void*)out,
                                                      nullptr, ATTN, w0, ctok);
  }
}

// Round 3
// 1869.386 us; speedup vs baseline: 1.1848x; 1.1848x over previous
//
#include <hip/hip_runtime.h>

typedef __attribute__((ext_vector_type(8))) short short8;
typedef __attribute__((ext_vector_type(4))) float f32x4;

#define GLBP(p) ((const __attribute__((address_space(1))) void*)(p))
#define LDSP(p) ((__attribute__((address_space(3))) void*)(p))

__device__ __forceinline__ float bf2f(unsigned short u) {
  return __uint_as_float(((unsigned int)u) << 16);
}
__device__ __forceinline__ unsigned short f2bf(float f) {
  unsigned int u = __float_as_uint(f);
  u += 0x7fff + ((u >> 16) & 1);
  return (unsigned short)(u >> 16);
}

// global token -> (batch, pixel-y, pixel-x); windows are 14x14, 5x5 grid/batch
__device__ __forceinline__ void tok2pix(int gt, int& b, int& py, int& px) {
  int w = gt / 196, t = gt - w * 196;
  b = w / 25;
  int wr = w - b * 25;
  int wy = wr / 5, wx = wr - wy * 5;
  int ty = t / 14;
  py = wy * 14 + ty;
  px = wx * 14 + (t - ty * 14);
}

// ---------------- weight transpose fp32(K,N) -> bf16(N,K) ----------------
__global__ void k_transpose(const float* __restrict__ W, unsigned short* __restrict__ Wt,
                            int K, int N) {
  __shared__ float tile[32][33];
  int tx = threadIdx.x, ty = threadIdx.y;
  int n0 = blockIdx.x * 32, k0 = blockIdx.y * 32;
#pragma unroll
  for (int i = 0; i < 4; ++i)
    tile[ty + 8 * i][tx] = W[(size_t)(k0 + ty + 8 * i) * N + n0 + tx];
  __syncthreads();
#pragma unroll
  for (int i = 0; i < 4; ++i)
    Wt[(size_t)(n0 + ty + 8 * i) * K + k0 + tx] = f2bf(tile[tx][ty + 8 * i]);
}

// ---------------- LN1 (windowed gather from image) -> bf16 token rows ----------------
__global__ __launch_bounds__(256) void k_ln1(const float* __restrict__ x,
                                             const float* __restrict__ g,
                                             const float* __restrict__ be,
                                             unsigned short* __restrict__ A1,
                                             int w0, int ctok) {
  int m = blockIdx.x, tid = threadIdx.x;
  int b, py, px;
  tok2pix(w0 * 196 + m, b, py, px);
  bool valid = (m < ctok) && (py < 64) && (px < 64);
  const float* row = x + ((size_t)((b * 64 + py) * 64 + px)) * 1280;
  float v[5];
#pragma unroll
  for (int i = 0; i < 5; ++i) v[i] = valid ? row[tid + 256 * i] : 0.f;
  float s = 0.f, ss = 0.f;
#pragma unroll
  for (int i = 0; i < 5; ++i) { s += v[i]; ss += v[i] * v[i]; }
#pragma unroll
  for (int o = 32; o > 0; o >>= 1) { s += __shfl_down(s, o); ss += __shfl_down(ss, o); }
  __shared__ float rs[8];
  int wid = tid >> 6, lane = tid & 63;
  if (lane == 0) { rs[wid] = s; rs[wid + 4] = ss; }
  __syncthreads();
  s = rs[0] + rs[1] + rs[2] + rs[3];
  ss = rs[4] + rs[5] + rs[6] + rs[7];
  float mu = s * (1.f / 1280.f);
  float var = ss * (1.f / 1280.f) - mu * mu;
  float rinv = rsqrtf(var + 1e-6f);
  unsigned short* o1 = A1 + (size_t)m * 1280;
#pragma unroll
  for (int i = 0; i < 5; ++i) {
    int c = tid + 256 * i;
    o1[c] = f2bf((v[i] - mu) * rinv * g[c] + be[c]);
  }
}

// ---------------- LN2 over bf16 attn_out rows -> bf16 ----------------
__global__ __launch_bounds__(256) void k_ln2(const unsigned short* __restrict__ AT,
                                             const float* __restrict__ g,
                                             const float* __restrict__ be,
                                             unsigned short* __restrict__ A2) {
  int m = blockIdx.x, tid = threadIdx.x;
  const unsigned short* row = AT + (size_t)m * 1280;
  float v[5];
#pragma unroll
  for (int i = 0; i < 5; ++i) v[i] = bf2f(row[tid + 256 * i]);
  float s = 0.f, ss = 0.f;
#pragma unroll
  for (int i = 0; i < 5; ++i) { s += v[i]; ss += v[i] * v[i]; }
#pragma unroll
  for (int o = 32; o > 0; o >>= 1) { s += __shfl_down(s, o); ss += __shfl_down(ss, o); }
  __shared__ float rs[8];
  int wid = tid >> 6, lane = tid & 63;
  if (lane == 0) { rs[wid] = s; rs[wid + 4] = ss; }
  __syncthreads();
  s = rs[0] + rs[1] + rs[2] + rs[3];
  ss = rs[4] + rs[5] + rs[6] + rs[7];
  float mu = s * (1.f / 1280.f);
  float var = ss * (1.f / 1280.f) - mu * mu;
  float rinv = rsqrtf(var + 1e-6f);
  unsigned short* o1 = A2 + (size_t)m * 1280;
#pragma unroll
  for (int i = 0; i < 5; ++i) {
    int c = tid + 256 * i;
    o1[c] = f2bf((v[i] - mu) * rinv * g[c] + be[c]);
  }
}

// ---------------- 256x256 bf16 GEMM, BK=32, 4-deep LDS pipeline, counted vmcnt ----------------
// C[M,N] = A[M,K] * Bt[N,K]^T
// EPI 0: +bias -> bf16 (QKV)         EPI 2: +bias + exact gelu -> bf16 (MLP1)
// EPI 1: +bias + window-residual(x) -> bf16 ATTN (proj)
// EPI 3: +bias + attn-residual -> f32 d_out, window->image crop (MLP2)
// LDS swizzle: byte ^= ((row>>1)&3)<<4 within each 64B row (both stage-source & ds_read).
template <int EPI>
__global__ __launch_bounds__(512, 2) void k_gemm256(const unsigned short* __restrict__ A,
                                                    const unsigned short* __restrict__ Bt,
                                                    int K, int N, int gx,
                                                    const float* __restrict__ bias,
                                                    void* __restrict__ outp,
                                                    const float* __restrict__ xres,
                                                    const unsigned short* __restrict__ attnres,
                                                    int w0, int ctok) {
  __shared__ __align__(16) char smem[131072];  // 4 bufs x (A 16K + B 16K)
  int tid = threadIdx.x;
  int w = tid >> 6, lane = tid & 63;
  // bijective XCD swizzle (m204)
  int nwg = gridDim.x, bid = blockIdx.x;
  int q = nwg >> 3, r = nwg & 7;
  int xcd = bid & 7, loc = bid >> 3;
  int wg = (xcd < r ? xcd * (q + 1) : r * (q + 1) + (xcd - r) * q) + loc;
  int bx = wg % gx, by = wg / gx;
  int mBase = by * 256, nBase = bx * 256;
  int wr = w >> 2, wc = w & 3;
  int la = lane & 15, lg = lane >> 4;

  // staging source geometry: thread covers LDS linear chunk (w*1024 + lane*16) of each 8KB issue
  int rS = w * 16 + (lane >> 2);                              // row within 128-row half
  int kbyte = (((lane & 3) ^ ((lane >> 3) & 3)) << 4);        // pre-swizzled k-chunk
  const char* Ab = (const char*)A;
  const char* Bb = (const char*)Bt;
  const char* pa0 = Ab + ((size_t)(mBase + rS) * K) * 2 + kbyte;
  const char* pa1 = Ab + ((size_t)(mBase + 128 + rS) * K) * 2 + kbyte;
  const char* pb0 = Bb + ((size_t)(nBase + rS) * K) * 2 + kbyte;
  const char* pb1 = Bb + ((size_t)(nBase + 128 + rS) * K) * 2 + kbyte;
  int ldsw = w * 1024;

  auto STAGE = [&](int t) {
    int b = (t & 3) * 32768;
    size_t ko = (size_t)t * 64;
    __builtin_amdgcn_global_load_lds(GLBP(pa0 + ko), LDSP(smem + b + ldsw), 16, 0, 0);
    __builtin_amdgcn_global_load_lds(GLBP(pa1 + ko), LDSP(smem + b + 8192 + ldsw), 16, 0, 0);
    __builtin_amdgcn_global_load_lds(GLBP(pb0 + ko), LDSP(smem + b + 16384 + ldsw), 16, 0, 0);
    __builtin_amdgcn_global_load_lds(GLBP(pb1 + ko), LDSP(smem + b + 24576 + ldsw), 16, 0, 0);
  };

  // swizzled fragment read offsets (constant per thread)
  int swz = ((lg ^ ((la >> 1) & 3)) << 4);
  int offA[8], offB[4];
#pragma unroll
  for (int m = 0; m < 8; ++m) offA[m] = (wr * 128 + m * 16 + la) * 64 + swz;
#pragma unroll
  for (int n = 0; n < 4; ++n) offB[n] = (wc * 64 + n * 16 + la) * 64 + swz;

  const f32x4 z4 = {0.f, 0.f, 0.f, 0.f};
  f32x4 acc[8][4];
#pragma unroll
  for (int m = 0; m < 8; ++m)
#pragma unroll
    for (int n = 0; n < 4; ++n) acc[m][n] = z4;

  int NT = K >> 5;
  STAGE(0);
  STAGE(1);
  STAGE(2);
  for (int t = 0; t < NT; ++t) {
    if (t + 2 < NT)
      asm volatile("s_waitcnt vmcnt(8)" ::: "memory");
    else if (t + 1 < NT)
      asm volatile("s_waitcnt vmcnt(4)" ::: "memory");
    else
      asm volatile("s_waitcnt vmcnt(0)" ::: "memory");
    __builtin_amdgcn_s_barrier();
    __builtin_amdgcn_sched_barrier(0);
    if (t + 3 < NT) STAGE(t + 3);
    const char* buf = (const char*)smem + (t & 3) * 32768;
    short8 af[8], bfr[4];
#pragma unroll
    for (int m = 0; m < 8; ++m) af[m] = *(const short8*)(buf + offA[m]);
#pragma unroll
    for (int n = 0; n < 4; ++n) bfr[n] = *(const short8*)(buf + 16384 + offB[n]);
    __builtin_amdgcn_s_setprio(1);
#pragma unroll
    for (int m = 0; m < 8; ++m)
#pragma unroll
      for (int n = 0; n < 4; ++n)
        acc[m][n] = __builtin_amdgcn_mfma_f32_16x16x32_bf16(af[m], bfr[n], acc[m][n], 0, 0, 0);
    __builtin_amdgcn_s_setprio(0);
  }

#pragma unroll
  for (int m = 0; m < 8; ++m) {
#pragma unroll
    for (int n = 0; n < 4; ++n) {
      int col = nBase + wc * 64 + n * 16 + la;
      float bcol = bias[col];
#pragma unroll
      for (int j = 0; j < 4; ++j) {
        int row = mBase + wr * 128 + m * 16 + lg * 4 + j;
        float v = acc[m][n][j] + bcol;
        if (EPI == 0) {
          ((unsigned short*)outp)[(size_t)row * N + col] = f2bf(v);
        } else if (EPI == 2) {
          float gg = 0.5f * v * (1.f + erff(v * 0.70710678118654752f));
          ((unsigned short*)outp)[(size_t)row * N + col] = f2bf(gg);
        } else if (EPI == 1) {
          if (row < ctok) {
            int b, py, px;
            tok2pix(w0 * 196 + row, b, py, px);
            float wv = (py < 64 && px < 64)
                           ? xres[((size_t)((b * 64 + py) * 64 + px)) * 1280 + col]
                           : 0.f;
            ((unsigned short*)outp)[(size_t)row * 1280 + col] = f2bf(v + wv);
          }
        } else {
          if (row < ctok) {
            int b, py, px;
            tok2pix(w0 * 196 + row, b, py, px);
            if (py < 64 && px < 64)
              ((float*)outp)[((size_t)((b * 64 + py) * 64 + px)) * 1280 + col] =
                  v + bf2f(attnres[(size_t)row * 1280 + col]);
          }
        }
      }
    }
  }
}

// ---------------- decomposed rel-pos bias: B[wh][t][0..13]=bias_h(ky), [14..27]=bias_w(kx) ----------------
__global__ __launch_bounds__(256) void k_relbias(const unsigned short* __restrict__ qkv,
                                                 const float* __restrict__ rph,
                                                 const float* __restrict__ rpw,
                                                 float* __restrict__ B) {
  int wh = blockIdx.x;
  int w = wh >> 4, nh = wh & 15;
  const unsigned short* qb = qkv + (size_t)w * 196 * 3840 + nh * 80;
  for (int id = threadIdx.x; id < 196 * 28; id += 256) {
    int t = id / 28, which = id - t * 28;
    int y = t / 14, xx = t - y * 14;
    const float* R = (which < 14) ? (rph + (size_t)(y - which + 13) * 80)
                                  : (rpw + (size_t)(xx - (which - 14) + 13) * 80);
    const unsigned short* q = qb + (size_t)t * 3840;
    float acc = 0.f;
#pragma unroll
    for (int d8 = 0; d8 < 10; ++d8) {
      short8 qv = *(const short8*)(q + d8 * 8);
      const float4* Rv = (const float4*)(R + d8 * 8);
      float4 ra = Rv[0], rb = Rv[1];
      acc += bf2f((unsigned short)qv[0]) * ra.x + bf2f((unsigned short)qv[1]) * ra.y +
             bf2f((unsigned short)qv[2]) * ra.z + bf2f((unsigned short)qv[3]) * ra.w +
             bf2f((unsigned short)qv[4]) * rb.x + bf2f((unsigned short)qv[5]) * rb.y +
             bf2f((unsigned short)qv[6]) * rb.z + bf2f((unsigned short)qv[7]) * rb.w;
    }
    B[(size_t)wh * (196 * 28) + id] = acc;
  }
}

// ---------------- attention: one block per (window, head) ----------------
__global__ __launch_bounds__(256) void k_attn(const unsigned short* __restrict__ qkv,
                                              const float* __restrict__ Bias,
                                              unsigned short* __restrict__ AO) {
  __shared__ unsigned short Qs[208 * 96];
  __shared__ unsigned short Ks[208 * 96];
  __shared__ unsigned short Vt[80 * 224];
  __shared__ unsigned short Ps[4][16 * 224];
  int wh = blockIdx.x;
  int w = wh >> 4, nh = wh & 15;
  int tid = threadIdx.x, wid = tid >> 6, lane = tid & 63;
  const unsigned short* base = qkv + (size_t)w * 196 * 3840 + nh * 80;
  short8 z8 = {0, 0, 0, 0, 0, 0, 0, 0};
  for (int c = tid; c < 208 * 12; c += 256) {
    int t = c / 12, d8 = (c - t * 12) * 8;
    short8 qv = z8, kv = z8;
    if (t < 196 && d8 < 80) {
      const unsigned short* p = base + (size_t)t * 3840 + d8;
      qv = *(const short8*)(p);
      kv = *(const short8*)(p + 1280);
    }
    *(short8*)(Qs + t * 96 + d8) = qv;
    *(short8*)(Ks + t * 96 + d8) = kv;
  }
  for (int c = tid; c < 208 * 10; c += 256) {
    int t = c / 10, d8 = (c - t * 10) * 8;
    short8 vv = z8;
    if (t < 196) vv = *(const short8*)(base + (size_t)t * 3840 + 2560 + d8);
#pragma unroll
    for (int e = 0; e < 8; ++e) Vt[(d8 + e) * 224 + t] = (unsigned short)vv[e];
  }
  for (int i = tid; i < 80 * 16; i += 256) Vt[(i >> 4) * 224 + 208 + (i & 15)] = 0;
  __syncthreads();

  int la = lane & 15, lg = lane >> 4;
  const float scale = 0.111803398874989485f;  // 80^-0.5
  const f32x4 z4 = {0.f, 0.f, 0.f, 0.f};
  unsigned short* P = Ps[wid];

  for (int rb = wid; rb < 13; rb += 4) {
    f32x4 s[13];
#pragma unroll
    for (int i = 0; i < 13; ++i) s[i] = z4;
#pragma unroll
    for (int kk = 0; kk < 3; ++kk) {
      short8 a = *(const short8*)(Qs + (rb * 16 + la) * 96 + kk * 32 + lg * 8);
#pragma unroll
      for (int ni = 0; ni < 13; ++ni) {
        short8 bb = *(const short8*)(Ks + (ni * 16 + la) * 96 + kk * 32 + lg * 8);
        s[ni] = __builtin_amdgcn_mfma_f32_16x16x32_bf16(a, bb, s[ni], 0, 0, 0);
      }
    }
#pragma unroll
    for (int j = 0; j < 4; ++j) {
      int rloc = lg * 4 + j;
      int t = rb * 16 + rloc;
      float v[13];
      float mx = -3e30f;
#pragma unroll
      for (int ci = 0; ci < 13; ++ci) {
        int key = ci * 16 + la;
        float val = s[ci][j] * scale;
        if (key < 196 && t < 196) {
          const float* Bp = Bias + ((size_t)wh * 196 + t) * 28;
          int ky = key / 14, kx = key - ky * 14;
          val += Bp[ky] + Bp[14 + kx];
        }
        if (key >= 196) val = -3e30f;
        v[ci] = val;
        mx = fmaxf(mx, val);
      }
#pragma unroll
      for (int o = 1; o < 16; o <<= 1) mx = fmaxf(mx, __shfl_xor(mx, o));
      float sum = 0.f;
#pragma unroll
      for (int ci = 0; ci < 13; ++ci) {
        float e = __expf(v[ci] - mx);
        v[ci] = e;
        sum += e;
      }
#pragma unroll
      for (int o = 1; o < 16; o <<= 1) sum += __shfl_xor(sum, o);
      float inv = 1.f / sum;
#pragma unroll
      for (int ci = 0; ci < 13; ++ci) P[rloc * 224 + ci * 16 + la] = f2bf(v[ci] * inv);
      P[rloc * 224 + 208 + la] = 0;
    }
    f32x4 o5[5];
#pragma unroll
    for (int i = 0; i < 5; ++i) o5[i] = z4;
#pragma unroll
    for (int kc = 0; kc < 7; ++kc) {
      short8 a = *(const short8*)(P + la * 224 + kc * 32 + lg * 8);
#pragma unroll
      for (int ni = 0; ni < 5; ++ni) {
        short8 bb = *(const short8*)(Vt + (ni * 16 + la) * 224 + kc * 32 + lg * 8);
        o5[ni] = __builtin_amdgcn_mfma_f32_16x16x32_bf16(a, bb, o5[ni], 0, 0, 0);
      }
    }
#pragma unroll
    for (int ni = 0; ni < 5; ++ni)
#pragma unroll
      for (int j = 0; j < 4; ++j) {
        int t = rb * 16 + lg * 4 + j;
        if (t < 196)
          AO[((size_t)w * 196 + t) * 1280 + nh * 80 + ni * 16 + la] = f2bf(o5[ni][j]);
      }
  }
}

extern "C" void kernel_launch(void* const* d_in, const int* in_sizes, int n_in,
                              void* d_out, int out_size, void* d_ws, size_t ws_size,
                              hipStream_t stream) {
  const float* x = (const float*)d_in[0];
  const float* ln1g = (const float*)d_in[1];
  const float* ln1b = (const float*)d_in[2];
  const float* qkvw = (const float*)d_in[3];
  const float* qkvb = (const float*)d_in[4];
  const float* projw = (const float*)d_in[5];
  const float* projb = (const float*)d_in[6];
  const float* rph = (const float*)d_in[7];
  const float* rpw = (const float*)d_in[8];
  const float* ln2g = (const float*)d_in[9];
  const float* ln2b = (const float*)d_in[10];
  const float* w1 = (const float*)d_in[11];
  const float* b1 = (const float*)d_in[12];
  const float* w2 = (const float*)d_in[13];
  const float* b2 = (const float*)d_in[14];
  float* out = (float*)d_out;

  const size_t woff = (3840ull * 1280 + 1280ull * 1280 + 5120ull * 1280 + 1280ull * 5120) * 2;
  // windows-per-chunk chosen to fit ws_size; Mb multiple of 256 for the 256-tile GEMM
  const int NWopts[7] = {100, 50, 25, 10, 5, 2, 1};
  int NW = 0, Mb = 0;
  for (int i = 0; i < 7; ++i) {
    int nw = NWopts[i];
    int mb = ((nw * 196 + 255) / 256) * 256;
    size_t tot = woff + (size_t)mb * 2560 /*A1*/ + (size_t)mb * 7680 /*QKV*/ +
                 (size_t)mb * 2560 /*AO*/ + (size_t)nw * 16 * 196 * 28 * 4 /*BIAS*/ +
                 (size_t)mb * 2560 /*ATTN*/;
    if (tot <= ws_size) { NW = nw; Mb = mb; break; }
  }
  if (!NW) return;  // ws_size too small to run at all

  char* p = (char*)d_ws;
  unsigned short* qkvwT = (unsigned short*)p; p += 3840ull * 1280 * 2;
  unsigned short* projwT = (unsigned short*)p; p += 1280ull * 1280 * 2;
  unsigned short* w1T = (unsigned short*)p; p += 5120ull * 1280 * 2;
  unsigned short* w2T = (unsigned short*)p; p += 1280ull * 5120 * 2;
  unsigned short* A1 = (unsigned short*)p; p += (size_t)Mb * 2560;
  unsigned short* QKV = (unsigned short*)p; p += (size_t)Mb * 7680;
  unsigned short* AO = (unsigned short*)p; p += (size_t)Mb * 2560;
  float* BIAS = (float*)p; p += (size_t)NW * 16 * 196 * 28 * 4;
  unsigned short* ATTN = (unsigned short*)p;
  unsigned short* Hb = QKV;  // MLP hidden (Mb x 5120) overlays QKV+AO (contiguous, both dead)
  unsigned short* A2 = A1;   // LN2 out overlays LN1 out (dead after QKV GEMM)

  k_transpose<<<dim3(120, 40), dim3(32, 8), 0, stream>>>(qkvw, qkvwT, 1280, 3840);
  k_transpose<<<dim3(40, 40), dim3(32, 8), 0, stream>>>(projw, projwT, 1280, 1280);
  k_transpose<<<dim3(160, 40), dim3(32, 8), 0, stream>>>(w1, w1T, 1280, 5120);
  k_transpose<<<dim3(40, 160), dim3(32, 8), 0, stream>>>(w2, w2T, 5120, 1280);

  int gy = Mb / 256;
  int nchunks = (100 + NW - 1) / NW;
  for (int c = 0; c < nchunks; ++c) {
    int w0 = c * NW;
    int cw = (100 - w0 < NW) ? (100 - w0) : NW;
    int ctok = cw * 196;
    k_ln1<<<Mb, 256, 0, stream>>>(x, ln1g, ln1b, A1, w0, ctok);
    k_gemm256<0><<<15 * gy, 512, 0, stream>>>(A1, qkvwT, 1280, 3840, 15, qkvb, (void*)QKV,
                                              nullptr, nullptr, 0, 0);
    k_relbias<<<cw * 16, 256, 0, stream>>>(QKV, rph, rpw, BIAS);
    k_attn<<<cw * 16, 256, 0, stream>>>(QKV, BIAS, AO);
    k_gemm256<1><<<5 * gy, 512, 0, stream>>>(AO, projwT, 1280, 1280, 5, projb, (void*)ATTN,
                                             x, nullptr, w0, ctok);
    k_ln2<<<Mb, 256, 0, stream>>>(ATTN, ln2g, ln2b, A2);
    k_gemm256<2><<<20 * gy, 512, 0, stream>>>(A2, w1T, 1280, 5120, 20, b1, (void*)Hb,
                                              nullptr, nullptr, 0, 0);
    k_gemm256<3><<<5 * gy, 512, 0, stream>>>(Hb, w2T, 5120, 1280, 5, b2, (void*)out,
                                             nullptr, ATTN, w0, ctok);
  }
}

// Round 4
// 1730.402 us; speedup vs baseline: 1.2800x; 1.0803x over previous
//
#include <hip/hip_runtime.h>

typedef __attribute__((ext_vector_type(8))) short short8;
typedef __attribute__((ext_vector_type(4))) float f32x4;

#define GLBP(p) ((const __attribute__((address_space(1))) void*)(p))
#define LDSP(p) ((__attribute__((address_space(3))) void*)(p))

__device__ __forceinline__ float bf2f(unsigned short u) {
  return __uint_as_float(((unsigned int)u) << 16);
}
__device__ __forceinline__ unsigned short f2bf(float f) {
  unsigned int u = __float_as_uint(f);
  u += 0x7fff + ((u >> 16) & 1);
  return (unsigned short)(u >> 16);
}

// global token -> (batch, pixel-y, pixel-x); windows are 14x14, 5x5 grid/batch
__device__ __forceinline__ void tok2pix(int gt, int& b, int& py, int& px) {
  int w = gt / 196, t = gt - w * 196;
  b = w / 25;
  int wr = w - b * 25;
  int wy = wr / 5, wx = wr - wy * 5;
  int ty = t / 14;
  py = wy * 14 + ty;
  px = wx * 14 + (t - ty * 14);
}

// ---------------- weight transpose fp32(K,N) -> bf16(N,K) ----------------
__global__ void k_transpose(const float* __restrict__ W, unsigned short* __restrict__ Wt,
                            int K, int N) {
  __shared__ float tile[32][33];
  int tx = threadIdx.x, ty = threadIdx.y;
  int n0 = blockIdx.x * 32, k0 = blockIdx.y * 32;
#pragma unroll
  for (int i = 0; i < 4; ++i)
    tile[ty + 8 * i][tx] = W[(size_t)(k0 + ty + 8 * i) * N + n0 + tx];
  __syncthreads();
#pragma unroll
  for (int i = 0; i < 4; ++i)
    Wt[(size_t)(n0 + ty + 8 * i) * K + k0 + tx] = f2bf(tile[tx][ty + 8 * i]);
}

// ---------------- LN1 (windowed gather from image) -> bf16 token rows ----------------
__global__ __launch_bounds__(256) void k_ln1(const float* __restrict__ x,
                                             const float* __restrict__ g,
                                             const float* __restrict__ be,
                                             unsigned short* __restrict__ A1,
                                             int w0, int ctok) {
  int m = blockIdx.x, tid = threadIdx.x;
  int b, py, px;
  tok2pix(w0 * 196 + m, b, py, px);
  bool valid = (m < ctok) && (py < 64) && (px < 64);
  const float* row = x + ((size_t)((b * 64 + py) * 64 + px)) * 1280;
  float v[5];
#pragma unroll
  for (int i = 0; i < 5; ++i) v[i] = valid ? row[tid + 256 * i] : 0.f;
  float s = 0.f, ss = 0.f;
#pragma unroll
  for (int i = 0; i < 5; ++i) { s += v[i]; ss += v[i] * v[i]; }
#pragma unroll
  for (int o = 32; o > 0; o >>= 1) { s += __shfl_down(s, o); ss += __shfl_down(ss, o); }
  __shared__ float rs[8];
  int wid = tid >> 6, lane = tid & 63;
  if (lane == 0) { rs[wid] = s; rs[wid + 4] = ss; }
  __syncthreads();
  s = rs[0] + rs[1] + rs[2] + rs[3];
  ss = rs[4] + rs[5] + rs[6] + rs[7];
  float mu = s * (1.f / 1280.f);
  float var = ss * (1.f / 1280.f) - mu * mu;
  float rinv = rsqrtf(var + 1e-6f);
  unsigned short* o1 = A1 + (size_t)m * 1280;
#pragma unroll
  for (int i = 0; i < 5; ++i) {
    int c = tid + 256 * i;
    o1[c] = f2bf((v[i] - mu) * rinv * g[c] + be[c]);
  }
}

// ---------------- LN2 over bf16 attn_out rows -> bf16 ----------------
__global__ __launch_bounds__(256) void k_ln2(const unsigned short* __restrict__ AT,
                                             const float* __restrict__ g,
                                             const float* __restrict__ be,
                                             unsigned short* __restrict__ A2) {
  int m = blockIdx.x, tid = threadIdx.x;
  const unsigned short* row = AT + (size_t)m * 1280;
  float v[5];
#pragma unroll
  for (int i = 0; i < 5; ++i) v[i] = bf2f(row[tid + 256 * i]);
  float s = 0.f, ss = 0.f;
#pragma unroll
  for (int i = 0; i < 5; ++i) { s += v[i]; ss += v[i] * v[i]; }
#pragma unroll
  for (int o = 32; o > 0; o >>= 1) { s += __shfl_down(s, o); ss += __shfl_down(ss, o); }
  __shared__ float rs[8];
  int wid = tid >> 6, lane = tid & 63;
  if (lane == 0) { rs[wid] = s; rs[wid + 4] = ss; }
  __syncthreads();
  s = rs[0] + rs[1] + rs[2] + rs[3];
  ss = rs[4] + rs[5] + rs[6] + rs[7];
  float mu = s * (1.f / 1280.f);
  float var = ss * (1.f / 1280.f) - mu * mu;
  float rinv = rsqrtf(var + 1e-6f);
  unsigned short* o1 = A2 + (size_t)m * 1280;
#pragma unroll
  for (int i = 0; i < 5; ++i) {
    int c = tid + 256 * i;
    o1[c] = f2bf((v[i] - mu) * rinv * g[c] + be[c]);
  }
}

// ---------------- 256x256 bf16 GEMM, BK=32, 4-deep ring, 2-phase interleave ----------------
// C[M,N] = A[M,K] * Bt[N,K]^T
// EPI 0: +bias -> bf16 (QKV)         EPI 2: +bias + exact gelu -> bf16 (MLP1)
// EPI 1: +bias + window-residual(x) -> bf16 ATTN (proj)
// EPI 3: +bias + attn-residual -> f32 d_out, window->image crop (MLP2)
template <int EPI>
__global__ __launch_bounds__(512, 2) void k_gemm256(const unsigned short* __restrict__ A,
                                                    const unsigned short* __restrict__ Bt,
                                                    int K, int N, int gx,
                                                    const float* __restrict__ bias,
                                                    void* __restrict__ outp,
                                                    const float* __restrict__ xres,
                                                    const unsigned short* __restrict__ attnres,
                                                    int w0, int ctok) {
  __shared__ __align__(16) char smem[131072];  // 4 bufs x (A 16K + B 16K)
  int tid = threadIdx.x;
  int w = tid >> 6, lane = tid & 63;
  // bijective XCD swizzle (m204)
  int nwg = gridDim.x, bid = blockIdx.x;
  int q = nwg >> 3, r = nwg & 7;
  int xcd = bid & 7, loc = bid >> 3;
  int wg = (xcd < r ? xcd * (q + 1) : r * (q + 1) + (xcd - r) * q) + loc;
  int bx = wg % gx, by = wg / gx;
  int mBase = by * 256, nBase = bx * 256;
  int wr = w >> 2, wc = w & 3;
  int la = lane & 15, lg = lane >> 4;

  // staging source geometry: thread covers LDS linear chunk (w*1024 + lane*16) of each 8KB issue
  int rS = w * 16 + (lane >> 2);                        // row within 128-row half
  int kbyte = (((lane & 3) ^ ((lane >> 3) & 3)) << 4);  // pre-swizzled k-chunk
  const char* Ab = (const char*)A;
  const char* Bb = (const char*)Bt;
  const char* pa0 = Ab + ((size_t)(mBase + rS) * K) * 2 + kbyte;
  const char* pa1 = Ab + ((size_t)(mBase + 128 + rS) * K) * 2 + kbyte;
  const char* pb0 = Bb + ((size_t)(nBase + rS) * K) * 2 + kbyte;
  const char* pb1 = Bb + ((size_t)(nBase + 128 + rS) * K) * 2 + kbyte;
  int ldsw = w * 1024;

  auto STAGE = [&](int t) {
    int b = (t & 3) * 32768;
    size_t ko = (size_t)t * 64;
    __builtin_amdgcn_global_load_lds(GLBP(pa0 + ko), LDSP(smem + b + ldsw), 16, 0, 0);
    __builtin_amdgcn_global_load_lds(GLBP(pa1 + ko), LDSP(smem + b + 8192 + ldsw), 16, 0, 0);
    __builtin_amdgcn_global_load_lds(GLBP(pb0 + ko), LDSP(smem + b + 16384 + ldsw), 16, 0, 0);
    __builtin_amdgcn_global_load_lds(GLBP(pb1 + ko), LDSP(smem + b + 24576 + ldsw), 16, 0, 0);
  };

  // swizzled fragment read offsets (constant per thread)
  int swz = ((lg ^ ((la >> 1) & 3)) << 4);
  int offA[8], offB[4];
#pragma unroll
  for (int m = 0; m < 8; ++m) offA[m] = (wr * 128 + m * 16 + la) * 64 + swz;
#pragma unroll
  for (int n = 0; n < 4; ++n) offB[n] = (wc * 64 + n * 16 + la) * 64 + swz;

  const f32x4 z4 = {0.f, 0.f, 0.f, 0.f};
  f32x4 acc[8][4];
#pragma unroll
  for (int m = 0; m < 8; ++m)
#pragma unroll
    for (int n = 0; n < 4; ++n) acc[m][n] = z4;

  int NT = K >> 5;
  STAGE(0);
  STAGE(1);
  STAGE(2);
  for (int t = 0; t < NT; ++t) {
    int rem = NT - 1 - t;
    if (rem >= 2)
      asm volatile("s_waitcnt vmcnt(8)" ::: "memory");
    else if (rem == 1)
      asm volatile("s_waitcnt vmcnt(4)" ::: "memory");
    else
      asm volatile("s_waitcnt vmcnt(0)" ::: "memory");
    __builtin_amdgcn_s_barrier();
    __builtin_amdgcn_sched_barrier(0);
    const char* buf = (const char*)smem + (t & 3) * 32768;
    short8 af[8], bfr[4];
    // phase 1: af0-3 + all B reads, stage t+3, MFMA quadrant m0-3 x n0-3
#pragma unroll
    for (int m = 0; m < 4; ++m) af[m] = *(const short8*)(buf + offA[m]);
#pragma unroll
    for (int n = 0; n < 4; ++n) bfr[n] = *(const short8*)(buf + 16384 + offB[n]);
    if (t + 3 < NT) STAGE(t + 3);
    __builtin_amdgcn_s_setprio(1);
#pragma unroll
    for (int m = 0; m < 4; ++m)
#pragma unroll
      for (int n = 0; n < 4; ++n)
        acc[m][n] = __builtin_amdgcn_mfma_f32_16x16x32_bf16(af[m], bfr[n], acc[m][n], 0, 0, 0);
    __builtin_amdgcn_s_setprio(0);
    __builtin_amdgcn_s_barrier();
    __builtin_amdgcn_sched_barrier(0);
    // phase 2: af4-7 reads, MFMA quadrant m4-7 x n0-3
#pragma unroll
    for (int m = 4; m < 8; ++m) af[m] = *(const short8*)(buf + offA[m]);
    __builtin_amdgcn_s_setprio(1);
#pragma unroll
    for (int m = 4; m < 8; ++m)
#pragma unroll
      for (int n = 0; n < 4; ++n)
        acc[m][n] = __builtin_amdgcn_mfma_f32_16x16x32_bf16(af[m], bfr[n], acc[m][n], 0, 0, 0);
    __builtin_amdgcn_s_setprio(0);
  }

#pragma unroll
  for (int m = 0; m < 8; ++m) {
#pragma unroll
    for (int n = 0; n < 4; ++n) {
      int col = nBase + wc * 64 + n * 16 + la;
      float bcol = bias[col];
#pragma unroll
      for (int j = 0; j < 4; ++j) {
        int row = mBase + wr * 128 + m * 16 + lg * 4 + j;
        float v = acc[m][n][j] + bcol;
        if (EPI == 0) {
          ((unsigned short*)outp)[(size_t)row * N + col] = f2bf(v);
        } else if (EPI == 2) {
          float gg = 0.5f * v * (1.f + erff(v * 0.70710678118654752f));
          ((unsigned short*)outp)[(size_t)row * N + col] = f2bf(gg);
        } else if (EPI == 1) {
          if (row < ctok) {
            int b, py, px;
            tok2pix(w0 * 196 + row, b, py, px);
            float wv = (py < 64 && px < 64)
                           ? xres[((size_t)((b * 64 + py) * 64 + px)) * 1280 + col]
                           : 0.f;
            ((unsigned short*)outp)[(size_t)row * 1280 + col] = f2bf(v + wv);
          }
        } else {
          if (row < ctok) {
            int b, py, px;
            tok2pix(w0 * 196 + row, b, py, px);
            if (py < 64 && px < 64)
              ((float*)outp)[((size_t)((b * 64 + py) * 64 + px)) * 1280 + col] =
                  v + bf2f(attnres[(size_t)row * 1280 + col]);
          }
        }
      }
    }
  }
}

// ---------------- decomposed rel-pos bias (bf16): B[wh][t][0..13]=bias_h(ky), [14..27]=bias_w(kx) ----------------
__global__ __launch_bounds__(256) void k_relbias(const unsigned short* __restrict__ qkv,
                                                 const float* __restrict__ rph,
                                                 const float* __restrict__ rpw,
                                                 unsigned short* __restrict__ B) {
  int wh = blockIdx.x;
  int w = wh >> 4, nh = wh & 15;
  const unsigned short* qb = qkv + (size_t)w * 196 * 3840 + nh * 80;
  for (int id = threadIdx.x; id < 196 * 28; id += 256) {
    int t = id / 28, which = id - t * 28;
    int y = t / 14, xx = t - y * 14;
    const float* R = (which < 14) ? (rph + (size_t)(y - which + 13) * 80)
                                  : (rpw + (size_t)(xx - (which - 14) + 13) * 80);
    const unsigned short* q = qb + (size_t)t * 3840;
    float acc = 0.f;
#pragma unroll
    for (int d8 = 0; d8 < 10; ++d8) {
      short8 qv = *(const short8*)(q + d8 * 8);
      const float4* Rv = (const float4*)(R + d8 * 8);
      float4 ra = Rv[0], rb = Rv[1];
      acc += bf2f((unsigned short)qv[0]) * ra.x + bf2f((unsigned short)qv[1]) * ra.y +
             bf2f((unsigned short)qv[2]) * ra.z + bf2f((unsigned short)qv[3]) * ra.w +
             bf2f((unsigned short)qv[4]) * rb.x + bf2f((unsigned short)qv[5]) * rb.y +
             bf2f((unsigned short)qv[6]) * rb.z + bf2f((unsigned short)qv[7]) * rb.w;
    }
    B[(size_t)wh * (196 * 28) + id] = f2bf(acc);
  }
}

// ---------------- attention: one block (512 thr, 8 waves) per (window, head) ----------------
__global__ __launch_bounds__(512) void k_attn(const unsigned short* __restrict__ qkv,
                                              const unsigned short* __restrict__ Bias,
                                              unsigned short* __restrict__ AO) {
  __shared__ unsigned short Ks[208 * 104];  // [key][d], zeros outside 196x80 (stride 52dw: 2-way)
  __shared__ unsigned short Vt[80 * 248];   // [d][key], keys>=196 zero (stride 124dw: 2-way)
  __shared__ unsigned short Ps[8][16 * 248];
  __shared__ unsigned short Bls[196 * 28];  // bf16 bias rows
  int wh = blockIdx.x;
  int w = wh >> 4, nh = wh & 15;
  int tid = threadIdx.x, wid = tid >> 6, lane = tid & 63;
  int la = lane & 15, lg = lane >> 4;
  const unsigned short* base = qkv + (size_t)w * 196 * 3840 + nh * 80;
  const short8 z8 = {0, 0, 0, 0, 0, 0, 0, 0};

  // K: 208 rows x 13 segs of 8 (cols 80..103 and rows >=196 zeroed)
  for (int c = tid; c < 208 * 13; c += 512) {
    int t = c / 13, seg = c - t * 13;
    short8 kv = z8;
    if (t < 196 && seg < 10) kv = *(const short8*)(base + (size_t)t * 3840 + 1280 + seg * 8);
    *(short8*)(Ks + t * 104 + seg * 8) = kv;
  }
  // V transposed: 28 t-blocks x 80 d, packed b128 writes
  for (int c = tid; c < 28 * 80; c += 512) {
    int d = c % 80, tb = c / 80;
    short8 pk;
#pragma unroll
    for (int e = 0; e < 8; ++e) {
      int t = tb * 8 + e;
      pk[e] = (t < 196) ? (short)base[(size_t)t * 3840 + 2560 + d] : (short)0;
    }
    *(short8*)(Vt + d * 248 + tb * 8) = pk;
  }
  // bias rows -> LDS
  for (int i = tid; i < 196 * 28; i += 512) Bls[i] = Bias[(size_t)wh * (196 * 28) + i];
  __syncthreads();

  // per-lane key decomposition (constant)
  int kyv[13], kxv[13];
#pragma unroll
  for (int ci = 0; ci < 13; ++ci) {
    int key = ci * 16 + la;
    kyv[ci] = key / 14;
    kxv[ci] = key - kyv[ci] * 14;
  }

  const float scale = 0.111803398874989485f;  // 80^-0.5
  const f32x4 z4 = {0.f, 0.f, 0.f, 0.f};
  unsigned short* P = Ps[wid];

  auto process = [&](int rb) {
    // Q fragments for this rb straight from global
    short8 qa[3];
#pragma unroll
    for (int kk = 0; kk < 3; ++kk) {
      int t = rb * 16 + la;
      int d = kk * 32 + lg * 8;
      qa[kk] = (t < 196 && d < 80) ? *(const short8*)(base + (size_t)t * 3840 + d) : z8;
    }
    f32x4 s[13];
#pragma unroll
    for (int i = 0; i < 13; ++i) s[i] = z4;
#pragma unroll
    for (int kk = 0; kk < 3; ++kk) {
#pragma unroll
      for (int ni = 0; ni < 13; ++ni) {
        short8 bb = *(const short8*)(Ks + (ni * 16 + la) * 104 + kk * 32 + lg * 8);
        s[ni] = __builtin_amdgcn_mfma_f32_16x16x32_bf16(qa[kk], bb, s[ni], 0, 0, 0);
      }
    }
#pragma unroll
    for (int j = 0; j < 4; ++j) {
      int rloc = lg * 4 + j;
      int t = rb * 16 + rloc;
      bool tval = t < 196;
      const unsigned short* Bp = Bls + (tval ? t : 0) * 28;
      float v[13];
      float mx = -3e30f;
#pragma unroll
      for (int ci = 0; ci < 13; ++ci) {
        int key = ci * 16 + la;
        float val = s[ci][j] * scale;
        if (key < 196 && tval) val += bf2f(Bp[kyv[ci]]) + bf2f(Bp[14 + kxv[ci]]);
        if (key >= 196) val = -3e30f;
        v[ci] = val;
        mx = fmaxf(mx, val);
      }
#pragma unroll
      for (int o = 1; o < 16; o <<= 1) mx = fmaxf(mx, __shfl_xor(mx, o));
      float sum = 0.f;
#pragma unroll
      for (int ci = 0; ci < 13; ++ci) {
        float e = __expf(v[ci] - mx);
        v[ci] = e;
        sum += e;
      }
#pragma unroll
      for (int o = 1; o < 16; o <<= 1) sum += __shfl_xor(sum, o);
      float inv = 1.f / sum;
#pragma unroll
      for (int ci = 0; ci < 13; ++ci) P[rloc * 248 + ci * 16 + la] = f2bf(v[ci] * inv);
      P[rloc * 248 + 208 + la] = 0;
    }
    f32x4 o5[5];
#pragma unroll
    for (int i = 0; i < 5; ++i) o5[i] = z4;
#pragma unroll
    for (int kc = 0; kc < 7; ++kc) {
      short8 a = *(const short8*)(P + la * 248 + kc * 32 + lg * 8);
#pragma unroll
      for (int ni = 0; ni < 5; ++ni) {
        short8 bb = *(const short8*)(Vt + (ni * 16 + la) * 248 + kc * 32 + lg * 8);
        o5[ni] = __builtin_amdgcn_mfma_f32_16x16x32_bf16(a, bb, o5[ni], 0, 0, 0);
      }
    }
#pragma unroll
    for (int ni = 0; ni < 5; ++ni)
#pragma unroll
      for (int j = 0; j < 4; ++j) {
        int t = rb * 16 + lg * 4 + j;
        if (t < 196)
          AO[((size_t)w * 196 + t) * 1280 + nh * 80 + ni * 16 + la] = f2bf(o5[ni][j]);
      }
  };

  process(wid);          // rb 0..7
  if (wid < 5) process(wid + 8);  // rb 8..12
}

extern "C" void kernel_launch(void* const* d_in, const int* in_sizes, int n_in,
                              void* d_out, int out_size, void* d_ws, size_t ws_size,
                              hipStream_t stream) {
  const float* x = (const float*)d_in[0];
  const float* ln1g = (const float*)d_in[1];
  const float* ln1b = (const float*)d_in[2];
  const float* qkvw = (const float*)d_in[3];
  const float* qkvb = (const float*)d_in[4];
  const float* projw = (const float*)d_in[5];
  const float* projb = (const float*)d_in[6];
  const float* rph = (const float*)d_in[7];
  const float* rpw = (const float*)d_in[8];
  const float* ln2g = (const float*)d_in[9];
  const float* ln2b = (const float*)d_in[10];
  const float* w1 = (const float*)d_in[11];
  const float* b1 = (const float*)d_in[12];
  const float* w2 = (const float*)d_in[13];
  const float* b2 = (const float*)d_in[14];
  float* out = (float*)d_out;

  const size_t woff = (3840ull * 1280 + 1280ull * 1280 + 5120ull * 1280 + 1280ull * 5120) * 2;
  // windows-per-chunk chosen to fit ws_size; Mb multiple of 256 for the 256-tile GEMM
  const int NWopts[7] = {100, 50, 25, 10, 5, 2, 1};
  int NW = 0, Mb = 0;
  for (int i = 0; i < 7; ++i) {
    int nw = NWopts[i];
    int mb = ((nw * 196 + 255) / 256) * 256;
    size_t tot = woff + (size_t)mb * 2560 /*A1*/ + (size_t)mb * 7680 /*QKV*/ +
                 (size_t)mb * 2560 /*AO*/ + (size_t)nw * 16 * 196 * 28 * 2 /*BIAS bf16*/ +
                 (size_t)mb * 2560 /*ATTN*/;
    if (tot <= ws_size) { NW = nw; Mb = mb; break; }
  }
  if (!NW) return;  // ws_size too small to run at all

  char* p = (char*)d_ws;
  unsigned short* qkvwT = (unsigned short*)p; p += 3840ull * 1280 * 2;
  unsigned short* projwT = (unsigned short*)p; p += 1280ull * 1280 * 2;
  unsigned short* w1T = (unsigned short*)p; p += 5120ull * 1280 * 2;
  unsigned short* w2T = (unsigned short*)p; p += 1280ull * 5120 * 2;
  unsigned short* A1 = (unsigned short*)p; p += (size_t)Mb * 2560;
  unsigned short* QKV = (unsigned short*)p; p += (size_t)Mb * 7680;
  unsigned short* AO = (unsigned short*)p; p += (size_t)Mb * 2560;
  unsigned short* BIAS = (unsigned short*)p; p += (size_t)NW * 16 * 196 * 28 * 2;
  unsigned short* ATTN = (unsigned short*)p;
  unsigned short* Hb = QKV;  // MLP hidden (Mb x 5120) overlays QKV+AO (contiguous, both dead)
  unsigned short* A2 = A1;   // LN2 out overlays LN1 out (dead after QKV GEMM)

  k_transpose<<<dim3(120, 40), dim3(32, 8), 0, stream>>>(qkvw, qkvwT, 1280, 3840);
  k_transpose<<<dim3(40, 40), dim3(32, 8), 0, stream>>>(projw, projwT, 1280, 1280);
  k_transpose<<<dim3(160, 40), dim3(32, 8), 0, stream>>>(w1, w1T, 1280, 5120);
  k_transpose<<<dim3(40, 160), dim3(32, 8), 0, stream>>>(w2, w2T, 5120, 1280);

  int gy = Mb / 256;
  int nchunks = (100 + NW - 1) / NW;
  for (int c = 0; c < nchunks; ++c) {
    int w0 = c * NW;
    int cw = (100 - w0 < NW) ? (100 - w0) : NW;
    int ctok = cw * 196;
    k_ln1<<<Mb, 256, 0, stream>>>(x, ln1g, ln1b, A1, w0, ctok);
    k_gemm256<0><<<15 * gy, 512, 0, stream>>>(A1, qkvwT, 1280, 3840, 15, qkvb, (void*)QKV,
                                              nullptr, nullptr, 0, 0);
    k_relbias<<<cw * 16, 256, 0, stream>>>(QKV, rph, rpw, BIAS);
    k_attn<<<cw * 16, 512, 0, stream>>>(QKV, BIAS, AO);
    k_gemm256<1><<<5 * gy, 512, 0, stream>>>(AO, projwT, 1280, 1280, 5, projb, (void*)ATTN,
                                             x, nullptr, w0, ctok);
    k_ln2<<<Mb, 256, 0, stream>>>(ATTN, ln2g, ln2b, A2);
    k_gemm256<2><<<20 * gy, 512, 0, stream>>>(A2, w1T, 1280, 5120, 20, b1, (void*)Hb,
                                              nullptr, nullptr, 0, 0);
    k_gemm256<3><<<5 * gy, 512, 0, stream>>>(Hb, w2T, 5120, 1280, 5, b2, (void*)out,
                                             nullptr, ATTN, w0, ctok);
  }
}